// Round 2
// baseline (231.201 us; speedup 1.0000x reference)
//
#include <hip/hip_runtime.h>
#include <hip/hip_cooperative_groups.h>

namespace cg = cooperative_groups;

// PercolationM: per-batch-element 256-bin histogram of [B,256,32,32] int32,
// output max bin count per batch element as float32. B=128, N=262144/batch.
//
// Round 4 strategy (vs R3's failed 128-block fusion):
//   R3 lesson: per-CU streaming BW is capped (~25 GB/s/CU) -> phase 1 must
//   cover all 256 CUs. R2 split (512 blk k1 + 128 blk k2) paid ~5us for the
//   k2 dispatch + gap + 512 KiB partial round-trip.
//   This round: ONE cooperative dispatch, 256 blocks x 1024 thr (1 block/CU,
//   guaranteed co-resident: 16 waves, 32 KiB LDS, ~40 VGPR). Each block
//   histograms HALF a batch element (BPB=2) into bank-exclusive 32-replica
//   LDS (lane i -> bank i%32, zero conflicts), replica-sums to a partial in
//   ws, grid.sync(), then blocks 0..127 sum their batch's 2 partials from L2
//   and block-max-reduce straight to out[b]. Deletes the k2 launch + gap.

#define NUM_BINS 256
#define NREP     32                // sub-histogram replicas (one per bank)
#define BPB      2                 // blocks per batch element
#define BLOCK    1024
#define N_PER_B  (256 * 32 * 32)   // 262144 elements per batch element
#define CHUNK    (N_PER_B / BPB)   // 131072 elements per block
#define NBATCH   128

__global__ __launch_bounds__(BLOCK) void
percolation_coop_kernel(const int* __restrict__ in, float* __restrict__ out,
                        int* __restrict__ part) {
    __shared__ int lh[NUM_BINS * NREP];   // 32 KiB

    for (int i = threadIdx.x; i < NUM_BINS * NREP; i += BLOCK)
        lh[i] = 0;
    __syncthreads();

    const int lane = threadIdx.x & (NREP - 1);    // bank-exclusive replica id

    const int4* p = (const int4*)(in + (size_t)blockIdx.x * CHUNK);
    const int iters = CHUNK / 4 / BLOCK;          // 32

#pragma unroll 8
    for (int i = 0; i < iters; ++i) {
        int4 v = p[(size_t)i * BLOCK + threadIdx.x];
        atomicAdd(&lh[v.x * NREP + lane], 1);
        atomicAdd(&lh[v.y * NREP + lane], 1);
        atomicAdd(&lh[v.z * NREP + lane], 1);
        atomicAdd(&lh[v.w * NREP + lane], 1);
    }
    __syncthreads();

    // Threads 0..255: sum 32 replicas per bin with rotated replica index
    // ((j+tid)&31 -> all lanes of a wave hit distinct banks), plain store.
    if (threadIdx.x < NUM_BINS) {
        int s = 0;
#pragma unroll
        for (int j = 0; j < NREP; ++j)
            s += lh[threadIdx.x * NREP + ((j + threadIdx.x) & (NREP - 1))];
        part[blockIdx.x * NUM_BINS + threadIdx.x] = s;
    }

    cg::this_grid().sync();

    // Phase 2: block b (b < 128) merges batch b's BPB partials (L2-resident)
    // and max-reduces. Threads >= 256 carry v=0 (counts >= 0, harmless).
    if (blockIdx.x < NBATCH) {
        int v = 0;
        if (threadIdx.x < NUM_BINS) {
            const int* q = part + (size_t)blockIdx.x * BPB * NUM_BINS;
#pragma unroll
            for (int s = 0; s < BPB; ++s)
                v += q[s * NUM_BINS + threadIdx.x];
        }

#pragma unroll
        for (int off = 32; off > 0; off >>= 1)
            v = max(v, __shfl_down(v, off, 64));

        __shared__ int wmax[BLOCK / 64];
        if ((threadIdx.x & 63) == 0)
            wmax[threadIdx.x >> 6] = v;
        __syncthreads();

        if (threadIdx.x == 0) {
            int m = wmax[0];
#pragma unroll
            for (int w = 1; w < BLOCK / 64; ++w)
                m = max(m, wmax[w]);
            out[blockIdx.x] = (float)m;
        }
    }
}

extern "C" void kernel_launch(void* const* d_in, const int* in_sizes, int n_in,
                              void* d_out, int out_size, void* d_ws, size_t ws_size,
                              hipStream_t stream) {
    const int* in   = (const int*)d_in[0];
    float*     out  = (float*)d_out;
    int*       part = (int*)d_ws;   // NBATCH*BPB*256 ints = 256 KiB, fully overwritten

    void* args[] = { (void*)&in, (void*)&out, (void*)&part };
    hipLaunchCooperativeKernel(percolation_coop_kernel,
                               dim3(NBATCH * BPB), dim3(BLOCK),
                               args, 0, stream);
}

// Round 3
// 207.122 us; speedup vs baseline: 1.1163x; 1.1163x over previous
//
#include <hip/hip_runtime.h>

// PercolationM: per-batch-element 256-bin histogram of [B,256,32,32] int32,
// output max bin count per batch element as float32. B=128, N=262144/batch.
//
// Round 5 strategy:
//   R3 lesson: per-CU streaming BW is capped (~25 GB/s/CU) -> need 512 blocks
//   (2/CU) streaming. R4 lesson: cooperative grid.sync costs tens of us on
//   this harness -> abandoned. This round keeps R2's k1 (512 blk x 1024 thr,
//   bank-exclusive 32-replica LDS histogram, zero conflicts) but replaces the
//   k2 dispatch with a last-block-done election:
//     - each block stores its 256-int partial with AGENT-scope stores
//       (bypass non-coherent per-XCD L2s, land at device coherence point)
//     - thread 0 fetch_add's a per-batch counter (AGENT, ACQ_REL); the 4th
//       arriver merges the batch's 4 partials and writes out[b] directly.
//   Merge overlaps with other batches still streaming (unlike k2, which
//   waited on the whole grid); only the last batch's merge is exposed.
//   The 128 counters are zeroed by a 512 B hipMemsetAsync (ws is re-poisoned
//   every iteration) -- cheaper than the k2 dispatch + gap it replaces.

#define NUM_BINS 256
#define NREP     32                // sub-histogram replicas (one per bank)
#define BPB      4                 // blocks per batch element
#define BLOCK    1024
#define N_PER_B  (256 * 32 * 32)   // 262144 elements per batch element
#define CHUNK    (N_PER_B / BPB)   // 65536 elements per block
#define NBATCH   128

__global__ __launch_bounds__(BLOCK) void
percolation_fused_kernel(const int* __restrict__ in, float* __restrict__ out,
                         int* __restrict__ part, int* __restrict__ cnt) {
    __shared__ int lh[NUM_BINS * NREP];   // 32 KiB
    __shared__ int elected;

    for (int i = threadIdx.x; i < NUM_BINS * NREP; i += BLOCK)
        lh[i] = 0;
    __syncthreads();

    const int lane = threadIdx.x & (NREP - 1);    // bank-exclusive replica id

    const int4* p = (const int4*)(in + (size_t)blockIdx.x * CHUNK);
    const int iters = CHUNK / 4 / BLOCK;          // 16

#pragma unroll 8
    for (int i = 0; i < iters; ++i) {
        int4 v = p[(size_t)i * BLOCK + threadIdx.x];
        atomicAdd(&lh[v.x * NREP + lane], 1);
        atomicAdd(&lh[v.y * NREP + lane], 1);
        atomicAdd(&lh[v.z * NREP + lane], 1);
        atomicAdd(&lh[v.w * NREP + lane], 1);
    }
    __syncthreads();

    const int batch = blockIdx.x >> 2;            // BPB = 4

    // Threads 0..255: sum 32 replicas per bin with rotated replica index
    // ((j+tid)&31 -> all lanes of a wave hit distinct banks). AGENT-scope
    // store -> visible device-wide (cross-XCD) at the coherence point.
    if (threadIdx.x < NUM_BINS) {
        int s = 0;
#pragma unroll
        for (int j = 0; j < NREP; ++j)
            s += lh[threadIdx.x * NREP + ((j + threadIdx.x) & (NREP - 1))];
        __hip_atomic_store(&part[blockIdx.x * NUM_BINS + threadIdx.x], s,
                           __ATOMIC_RELAXED, __HIP_MEMORY_SCOPE_AGENT);
    }
    __syncthreads();   // compiler drains vmcnt before barrier -> stores done

    if (threadIdx.x == 0) {
        int old = __hip_atomic_fetch_add(&cnt[batch], 1, __ATOMIC_ACQ_REL,
                                         __HIP_MEMORY_SCOPE_AGENT);
        elected = (old == BPB - 1);
    }
    __syncthreads();
    if (!elected) return;

    // Winner: merge this batch's BPB partials (L3-resident) and max-reduce.
    // Threads >= 256 carry v=0 (counts >= 0, harmless for the max).
    int v = 0;
    if (threadIdx.x < NUM_BINS) {
        const int* q = part + (size_t)batch * BPB * NUM_BINS;
#pragma unroll
        for (int s = 0; s < BPB; ++s)
            v += __hip_atomic_load(&q[s * NUM_BINS + threadIdx.x],
                                   __ATOMIC_RELAXED, __HIP_MEMORY_SCOPE_AGENT);
    }

#pragma unroll
    for (int off = 32; off > 0; off >>= 1)
        v = max(v, __shfl_down(v, off, 64));

    __shared__ int wmax[BLOCK / 64];
    if ((threadIdx.x & 63) == 0)
        wmax[threadIdx.x >> 6] = v;
    __syncthreads();

    if (threadIdx.x == 0) {
        int m = wmax[0];
#pragma unroll
        for (int w = 1; w < BLOCK / 64; ++w)
            m = max(m, wmax[w]);
        out[batch] = (float)m;
    }
}

extern "C" void kernel_launch(void* const* d_in, const int* in_sizes, int n_in,
                              void* d_out, int out_size, void* d_ws, size_t ws_size,
                              hipStream_t stream) {
    const int* in   = (const int*)d_in[0];
    float*     out  = (float*)d_out;
    int*       part = (int*)d_ws;                       // 512 KiB partials
    int*       cnt  = part + NBATCH * BPB * NUM_BINS;   // 128 counters

    hipMemsetAsync(cnt, 0, NBATCH * sizeof(int), stream);
    percolation_fused_kernel<<<NBATCH * BPB, BLOCK, 0, stream>>>(in, out, part, cnt);
}

// Round 4
// 187.487 us; speedup vs baseline: 1.2332x; 1.1047x over previous
//
#include <hip/hip_runtime.h>

// PercolationM: per-batch-element 256-bin histogram of [B,256,32,32] int32,
// output max bin count per batch element as float32. B=128, N=262144/batch.
//
// Round 6: restore the best-known structure (R2, 187.8us) + slim k2.
//   Session ledger:
//     R2  two-kernel split (this structure)            187.8us  <- best
//     R3  fused 128-block (per-CU BW cap ~26 GB/s/CU)  195.8us
//     R4  cooperative grid.sync                        231.2us
//     R5  scoped-atomic election (+fence cache-maint)  207.1us
//   Fixed costs: 2 harness ws-poison fills ~156us (present even when ws is
//   unused); k1 streams 128 MiB at the chip HBM roofline (~6.4 TB/s); the
//   second dispatch (~5.5us) is the cheapest known cross-block-sum boundary
//   (all three single-dispatch schemes regressed; counter-based schemes need
//   a memset node since ws is re-poisoned every iteration).
//   k1: 4 blocks/batch, 1024 thr, bank-exclusive 32-replica LDS histogram
//       (lane i -> bank i%32, zero conflicts), int4 coalesced loads, plain
//       partial store (fully overwritten -> no zeroing needed).
//   k2: single-wave blocks (128 x 64): lane owns 4 bins, 16 independent
//       coalesced loads (ILP covers L2/L3 latency), in-wave max reduce,
//       no LDS, no barrier.

#define NUM_BINS 256
#define NREP     32                // sub-histogram replicas (one per bank)
#define BPB      4                 // blocks per batch element
#define N_PER_B  (256 * 32 * 32)   // 262144 elements per batch element
#define CHUNK    (N_PER_B / BPB)   // 65536 elements per block
#define BLOCK1   1024
#define NBATCH   128

__global__ __launch_bounds__(BLOCK1) void
percolation_hist_kernel(const int* __restrict__ in, int* __restrict__ part) {
    __shared__ int lh[NUM_BINS * NREP];   // 32 KiB

    for (int i = threadIdx.x; i < NUM_BINS * NREP; i += BLOCK1)
        lh[i] = 0;
    __syncthreads();

    const int lane = threadIdx.x & (NREP - 1);    // bank-exclusive replica id

    const int4* p = (const int4*)(in + (size_t)blockIdx.x * CHUNK);
    const int iters = CHUNK / 4 / BLOCK1;         // 16

#pragma unroll 4
    for (int i = 0; i < iters; ++i) {
        int4 v = p[(size_t)i * BLOCK1 + threadIdx.x];
        atomicAdd(&lh[v.x * NREP + lane], 1);
        atomicAdd(&lh[v.y * NREP + lane], 1);
        atomicAdd(&lh[v.z * NREP + lane], 1);
        atomicAdd(&lh[v.w * NREP + lane], 1);
    }
    __syncthreads();

    // Threads 0..255: sum 32 replicas per bin with rotated replica index
    // ((j+tid)&31 -> all lanes of a wave hit distinct banks), plain store.
    if (threadIdx.x < NUM_BINS) {
        int s = 0;
#pragma unroll
        for (int j = 0; j < NREP; ++j)
            s += lh[threadIdx.x * NREP + ((j + threadIdx.x) & (NREP - 1))];
        part[blockIdx.x * NUM_BINS + threadIdx.x] = s;
    }
}

__global__ __launch_bounds__(64) void
percolation_max_kernel(const int* __restrict__ part, float* __restrict__ out) {
    const int batch = blockIdx.x;
    const int* p = part + (size_t)batch * BPB * NUM_BINS;

    // Each of the 64 lanes owns 4 bins; 16 independent coalesced loads.
    int m = 0;
#pragma unroll
    for (int j = 0; j < NUM_BINS / 64; ++j) {
        const int bin = threadIdx.x + 64 * j;
        int v = 0;
#pragma unroll
        for (int s = 0; s < BPB; ++s)
            v += p[s * NUM_BINS + bin];
        m = max(m, v);
    }

    // in-wave (64-lane) max reduce
#pragma unroll
    for (int off = 32; off > 0; off >>= 1)
        m = max(m, __shfl_down(m, off, 64));

    if (threadIdx.x == 0)
        out[batch] = (float)m;
}

extern "C" void kernel_launch(void* const* d_in, const int* in_sizes, int n_in,
                              void* d_out, int out_size, void* d_ws, size_t ws_size,
                              hipStream_t stream) {
    const int* in   = (const int*)d_in[0];
    float*     out  = (float*)d_out;
    int*       part = (int*)d_ws;   // B*BPB*256 ints = 512 KiB, fully overwritten

    const int B = out_size;         // 128

    percolation_hist_kernel<<<B * BPB, BLOCK1, 0, stream>>>(in, part);
    percolation_max_kernel<<<B, 64, 0, stream>>>(part, out);
}